// Round 13
// baseline (916.466 us; speedup 1.0000x reference)
//
#include <hip/hip_runtime.h>
#include <math.h>

#define DIN 128
#define DOUT 64

#define NBLK 64             // binning blocks
#define BK_SHIFT 7          // 128 cols per bucket
#define BK_COLS 128
#define NBK_STRIDE 1024     // blk_hist row stride (buckets padded)

__device__ __forceinline__ float safe_pow(float d, float e) {
    float p = powf(d, e);
    return isinf(p) ? 0.0f : p;
}

__device__ __forceinline__ float dot4(float4 a, float4 b) {
    return a.x * b.x + a.y * b.y + a.z * b.z + a.w * b.w;
}

// fp32 -> bf16 (round-to-nearest-even), as raw ushort
__device__ __forceinline__ unsigned short f32_to_bf16(float f) {
    unsigned bits = __float_as_uint(f);
    unsigned r = (bits + 0x7FFFu + ((bits >> 16) & 1u)) >> 16;
    return (unsigned short)r;
}
// bf16 (raw ushort) -> fp32
__device__ __forceinline__ float bf16_to_f32(unsigned short u) {
    return __uint_as_float((unsigned)u << 16);
}

// ---------------------------------------------------------------------------
// Plain multi-block 64x64 matmul: C = A @ B, Bsrc SYMMETRIC (rows read as
// cols). grid 8 (single) or 16 (dual: blocks 8..15 compute C2 = A2 @ B).
// Optional CB output (single passes only): CB = 1.5I - 0.5*C.
// ---------------------------------------------------------------------------
__global__ __launch_bounds__(256) void mm_pass(const float* A1, const float* A2,
                                               const float* Bsrc,
                                               float* C1, float* C2, float* CB) {
    int t = threadIdx.x;
    bool second = (blockIdx.x >= 8);
    int blk = blockIdx.x & 7;
    const float* As = second ? A2 : A1;
    float* Cs = second ? C2 : C1;
    int c = t & 63;
    int r0 = blk * 8 + (t >> 6) * 2;
    float acc0 = 0.f, acc1 = 0.f;
#pragma unroll
    for (int k4 = 0; k4 < 16; ++k4) {
        float4 b  = *(const float4*)&Bsrc[c * 64 + k4 * 4];
        float4 a0 = *(const float4*)&As[r0 * 64 + k4 * 4];
        float4 a1 = *(const float4*)&As[(r0 + 1) * 64 + k4 * 4];
        acc0 += dot4(a0, b);
        acc1 += dot4(a1, b);
    }
    Cs[r0 * 64 + c] = acc0;
    Cs[(r0 + 1) * 64 + c] = acc1;
    if (CB != nullptr && !second) {
        CB[r0 * 64 + c]       = ((r0 == c)     ? 1.5f : 0.0f) - 0.5f * acc0;
        CB[(r0 + 1) * 64 + c] = ((r0 + 1 == c) ? 1.5f : 0.0f) - 0.5f * acc1;
    }
}

// ---------------------------------------------------------------------------
// G = W @ W^T (64x64, K=128), 8 blocks.
// ---------------------------------------------------------------------------
__global__ __launch_bounds__(256) void gram_pass(const float* W, float* G) {
    int t = threadIdx.x;
    int c = t & 63;
    int r0 = blockIdx.x * 8 + (t >> 6) * 2;
    float acc0 = 0.f, acc1 = 0.f;
#pragma unroll
    for (int k4 = 0; k4 < 32; ++k4) {
        float4 b  = *(const float4*)&W[c * 128 + k4 * 4];
        float4 a0 = *(const float4*)&W[r0 * 128 + k4 * 4];
        float4 a1 = *(const float4*)&W[(r0 + 1) * 128 + k4 * 4];
        acc0 += dot4(a0, b);
        acc1 += dot4(a1, b);
    }
    G[r0 * 64 + c] = acc0;
    G[(r0 + 1) * 64 + c] = acc1;
}

// ---------------------------------------------------------------------------
// power iteration on H2 = G^4 (trace-scaled, 8 raw iters + Rayleigh), 1 wave.
// ---------------------------------------------------------------------------
__global__ __launch_bounds__(64) void power_pass(const float* gH2, float* gSc) {
    int t = threadIdx.x;
    float tr = gH2[t * 65];
#pragma unroll
    for (int d = 1; d < 64; d <<= 1) tr += __shfl_xor(tr, d);
    float inv_tr = 1.0f / tr;
    float4 g4[16];
#pragma unroll
    for (int j4 = 0; j4 < 16; ++j4) {
        float4 v = *(const float4*)&gH2[t * 64 + j4 * 4];
        v.x *= inv_tr; v.y *= inv_tr; v.z *= inv_tr; v.w *= inv_tr;
        g4[j4] = v;
    }
    unsigned h = (unsigned)t * 2654435761u;
    float xv = 0.5f + (float)((h >> 17) & 0x7fff) * (1.0f / 32768.0f);
    float yv = 0.f;
    for (int it = 0; it < 8; ++it) {
        float p0 = 0.f, p1 = 0.f, p2 = 0.f, p3 = 0.f;
#pragma unroll
        for (int j4 = 0; j4 < 16; ++j4) {
            float4 xx;
            xx.x = __shfl(xv, j4 * 4 + 0);
            xx.y = __shfl(xv, j4 * 4 + 1);
            xx.z = __shfl(xv, j4 * 4 + 2);
            xx.w = __shfl(xv, j4 * 4 + 3);
            float dd = dot4(g4[j4], xx);
            if (j4 < 4) p0 += dd; else if (j4 < 8) p1 += dd;
            else if (j4 < 12) p2 += dd; else p3 += dd;
        }
        yv = (p0 + p1) + (p2 + p3);
        if (it < 7) xv = yv;
    }
    float num = xv * yv, den = xv * xv;
#pragma unroll
    for (int d = 1; d < 64; d <<= 1) {
        num += __shfl_xor(num, d);
        den += __shfl_xor(den, d);
    }
    if (t == 0) {
        float lam_h2 = tr * num / den;        // = sigma^8
        float sig = powf(lam_h2, 0.125f);
        gSc[0] = 1.0f / (1.1f * sig);
        gSc[1] = 1.0f / (1.21f * sig * sig);
    }
}

// ---------------------------------------------------------------------------
// prep: A0 = rs*G;  B0 = 1.5I - 0.5*A0
// ---------------------------------------------------------------------------
__global__ __launch_bounds__(256) void prep_pass(const float* gG, const float* gSc,
                                                 float* gA0, float* gB0) {
    int idx = blockIdx.x * 256 + threadIdx.x;
    if (idx >= 4096) return;
    float rs = gSc[1];
    int r = idx >> 6, c = idx & 63;
    float a0 = rs * gG[idx];
    gA0[idx] = a0;
    gB0[idx] = ((r == c) ? 1.5f : 0.0f) - 0.5f * a0;
}

// ---------------------------------------------------------------------------
// Wo = sc * P @ W  (64x128), 8 blocks.
// ---------------------------------------------------------------------------
__global__ __launch_bounds__(256) void wo_pass(const float* W, const float* P,
                                               const float* gSc, float* Wo) {
    int t = threadIdx.x;
    int c = t & 63;
    int r0 = blockIdx.x * 8 + (t >> 6) * 2;
    float a00 = 0.f, a01 = 0.f, a10 = 0.f, a11 = 0.f;
#pragma unroll 4
    for (int j = 0; j < 64; ++j) {
        float p0 = P[r0 * 64 + j];
        float p1 = P[(r0 + 1) * 64 + j];
        float w0 = W[j * 128 + c];
        float w1 = W[j * 128 + c + 64];
        a00 += p0 * w0; a01 += p0 * w1;
        a10 += p1 * w0; a11 += p1 * w1;
    }
    float sc = gSc[0];
    Wo[r0 * 128 + c]            = sc * a00;
    Wo[r0 * 128 + c + 64]       = sc * a01;
    Wo[(r0 + 1) * 128 + c]      = sc * a10;
    Wo[(r0 + 1) * 128 + c + 64] = sc * a11;
}

// ---------------------------------------------------------------------------
// per-node prep
// ---------------------------------------------------------------------------
__global__ void node_prep(const float* __restrict__ diags,
                          const float* m1, const float* m2, const float* m3,
                          const float* e1, const float* e2, const float* e3,
                          float* __restrict__ d_e2m, float* __restrict__ d_e3p,
                          float* __restrict__ gso2, int n) {
    int i = blockIdx.x * blockDim.x + threadIdx.x;
    if (i >= n) return;
    float d = diags[i];
    float p1 = safe_pow(d, e1[0]);
    float p2 = safe_pow(d, e2[0]);
    float p3 = safe_pow(d, e3[0]);
    float vm2 = m2[0];
    d_e2m[i] = vm2 * p2;
    d_e3p[i] = p3;
    gso2[i] = m1[0] * p1 + vm2 * p2 * p3 + m3[0];
}

// ---------------------------------------------------------------------------
// xw = x @ Wo^T — register-tiled GEMM; OUTPUT IN BF16.
// ---------------------------------------------------------------------------
#define XN 64
#define XS 132
__global__ __launch_bounds__(256) void xw_kernel(const float* __restrict__ x,
                                                 const float* __restrict__ Wo,
                                                 unsigned short* __restrict__ xwb,
                                                 int n) {
    __shared__ __align__(16) float xs[XN * XS];
    __shared__ __align__(16) float ws[DOUT * XS];
    int t = threadIdx.x;
    int base = blockIdx.x * XN;
    for (int f = t; f < DOUT * (DIN / 4); f += 256) {
        int r = f >> 5, c = f & 31;
        *(float4*)&ws[r * XS + c * 4] = *(const float4*)&Wo[r * DIN + c * 4];
    }
    for (int f = t; f < XN * (DIN / 4); f += 256) {
        int r = f >> 5, c = f & 31;
        int node = base + r;
        float4 v = make_float4(0.f, 0.f, 0.f, 0.f);
        if (node < n) v = *(const float4*)&x[(size_t)node * DIN + c * 4];
        *(float4*)&xs[r * XS + c * 4] = v;
    }
    __syncthreads();
    int tn = t >> 4;
    int td = t & 15;
    float acc[4][4] = {};
#pragma unroll 2
    for (int k4 = 0; k4 < DIN / 4; ++k4) {
        float4 a[4], w[4];
#pragma unroll
        for (int r = 0; r < 4; ++r) a[r] = *(const float4*)&xs[(tn * 4 + r) * XS + k4 * 4];
#pragma unroll
        for (int c = 0; c < 4; ++c) w[c] = *(const float4*)&ws[(td + c * 16) * XS + k4 * 4];
#pragma unroll
        for (int r = 0; r < 4; ++r)
#pragma unroll
            for (int c = 0; c < 4; ++c) acc[r][c] += dot4(a[r], w[c]);
    }
#pragma unroll
    for (int r = 0; r < 4; ++r) {
        int node = base + tn * 4 + r;
        if (node >= n) break;
#pragma unroll
        for (int c = 0; c < 4; ++c)
            xwb[(size_t)node * DOUT + td + c * 16] = f32_to_bf16(acc[r][c]);
    }
}

// ---------------------------------------------------------------------------
// Sort pass B1: per-block bucket histograms (bucket = col >> 7).
// ---------------------------------------------------------------------------
__global__ __launch_bounds__(256) void b1_hist(const int* __restrict__ ei,
                                               unsigned* __restrict__ blk_hist,
                                               int e_cnt, int chunk, int nbk) {
    __shared__ int h[NBK_STRIDE];
    int b = blockIdx.x, t = threadIdx.x;
    for (int j = t; j < NBK_STRIDE; j += 256) h[j] = 0;
    __syncthreads();
    int lo = b * chunk, hi = min(lo + chunk, e_cnt);
    for (int e = lo + t; e < hi; e += 256)
        atomicAdd(&h[ei[e_cnt + e] >> BK_SHIFT], 1);
    __syncthreads();
    for (int j = t; j < nbk; j += 256)
        blk_hist[(size_t)b * NBK_STRIDE + j] = (unsigned)h[j];
}

// ---------------------------------------------------------------------------
// Sort pass S: scan bucket totals -> bucket_offsets + per-(block,bucket) bases.
// ---------------------------------------------------------------------------
__global__ __launch_bounds__(1024) void s_scan(unsigned* __restrict__ blk_hist,
                                               unsigned* __restrict__ bucket_offsets,
                                               int nbk, int e_cnt) {
    __shared__ int tot[1024];
    int t = threadIdx.x;
    int total = 0;
    if (t < nbk) {
        int run = 0;
        for (int b = 0; b < NBLK; ++b) {
            size_t idx = (size_t)b * NBK_STRIDE + t;
            int v = (int)blk_hist[idx];
            blk_hist[idx] = (unsigned)run;
            run += v;
        }
        total = run;
    }
    tot[t] = total;
    __syncthreads();
    for (int d = 1; d < 1024; d <<= 1) {
        int u = (t >= d) ? tot[t - d] : 0;
        __syncthreads();
        tot[t] += u;
        __syncthreads();
    }
    int excl = tot[t] - total;
    if (t < nbk) {
        bucket_offsets[t] = (unsigned)excl;
        for (int b = 0; b < NBLK; ++b)
            blk_hist[(size_t)b * NBK_STRIDE + t] += (unsigned)excl;
    }
    if (t == 0) bucket_offsets[nbk] = (unsigned)e_cnt;
}

// ---------------------------------------------------------------------------
// Sort pass B2: scatter (key = src<<7|lcol, weight = d_e2m[src]) uint2 pairs
// into reserved per-block runs. key & ~127 is directly the xwb byte offset.
// ---------------------------------------------------------------------------
__global__ __launch_bounds__(256) void b2_scatter(const int* __restrict__ ei,
                                                  const float* __restrict__ d_e2m,
                                                  const unsigned* __restrict__ blk_hist,
                                                  uint2* __restrict__ pairs,
                                                  int e_cnt, int chunk, int nbk) {
    __shared__ int cur[NBK_STRIDE];
    int b = blockIdx.x, t = threadIdx.x;
    for (int j = t; j < nbk; j += 256)
        cur[j] = (int)blk_hist[(size_t)b * NBK_STRIDE + j];
    __syncthreads();
    int lo = b * chunk, hi = min(lo + chunk, e_cnt);
    for (int e = lo + t; e < hi; e += 256) {
        int col = ei[e_cnt + e];
        int src = ei[e];
        int bkt = col >> BK_SHIFT;
        int pos = atomicAdd(&cur[bkt], 1);
        uint2 o;
        o.x = ((unsigned)src << BK_SHIFT) | (unsigned)(col & (BK_COLS - 1));
        o.y = __float_as_uint(d_e2m[src]);
        pairs[pos] = o;
    }
}

// ---------------------------------------------------------------------------
// Bucket gather: one 512-thread block (8 waves) per bucket.
// LDS acc[128 cols][64 dims] (32KB); waves stream the bucket's edges
// (unroll 4) accumulating w * xw[src] via LDS float atomics; epilogue fuses
// self-loop + bias + log-softmax. No CSR, no per-node loop drain.
// ---------------------------------------------------------------------------
__global__ __launch_bounds__(512) void bucket_gather(const uint2* __restrict__ pairs,
                                                     const unsigned* __restrict__ boff,
                                                     const float* __restrict__ d_e3p,
                                                     const unsigned short* __restrict__ xwb,
                                                     const float* __restrict__ gso2,
                                                     const float* __restrict__ bias,
                                                     float* __restrict__ out, int n) {
    __shared__ float acc[BK_COLS * DOUT];   // 32 KB
    int t = threadIdx.x;
    unsigned lane = t & 63;
    int wv = t >> 6;                        // 0..7
    int bk = blockIdx.x;
    // zero accumulators (512 threads x 16 floats)
    for (int q = t * 4; q < BK_COLS * DOUT; q += 512 * 4)
        *(float4*)&acc[q] = make_float4(0.f, 0.f, 0.f, 0.f);
    __syncthreads();

    int base = (int)boff[bk];
    int cnt = (int)boff[bk + 1] - base;
    const unsigned short* xw0 = xwb;
    // wave wv handles edge indices {wv*4 + j + 32*k}
    for (int k = wv * 4; k < cnt; k += 32) {
#pragma unroll
        for (int j = 0; j < 4; ++j) {
            int idx = k + j;
            if (idx < cnt) {
                uint2 p = pairs[base + idx];
                float w = __uint_as_float(p.y);
                unsigned rowb = p.x & ~(unsigned)(BK_COLS - 1);   // src * 128 bytes
                float a = bf16_to_f32(*(const unsigned short*)((const char*)xw0 + rowb + lane * 2));
                unsigned lcol = p.x & (BK_COLS - 1);
                atomicAdd(&acc[(lcol << 6) + lane], w * a);
            }
        }
    }
    __syncthreads();

    // epilogue: 8 waves x 16 cols
    float b2 = 2.0f * bias[lane];
    for (int lcol = wv; lcol < BK_COLS; lcol += 8) {
        int node = bk * BK_COLS + lcol;
        if (node >= n) continue;
        float xself = bf16_to_f32(xwb[(size_t)node * DOUT + lane]);
        float v = gso2[node] * xself + b2 + d_e3p[node] * acc[(lcol << 6) + lane];
        float m = v;
#pragma unroll
        for (int d = 1; d < 64; d <<= 1) m = fmaxf(m, __shfl_xor(m, d));
        float s = expf(v - m);
#pragma unroll
        for (int d = 1; d < 64; d <<= 1) s += __shfl_xor(s, d);
        out[(size_t)node * DOUT + lane] = v - m - logf(s);
    }
}

// ---------------------------------------------------------------------------
extern "C" void kernel_launch(void* const* d_in, const int* in_sizes, int n_in,
                              void* d_out, int out_size, void* d_ws, size_t ws_size,
                              hipStream_t stream) {
    const float* x     = (const float*)d_in[0];
    const int*   ei    = (const int*)d_in[1];
    const float* diags = (const float*)d_in[3];
    const float* W     = (const float*)d_in[4];
    const float* b     = (const float*)d_in[5];
    const float* m1    = (const float*)d_in[6];
    const float* m2    = (const float*)d_in[7];
    const float* m3    = (const float*)d_in[8];
    const float* e1    = (const float*)d_in[9];
    const float* e2    = (const float*)d_in[10];
    const float* e3    = (const float*)d_in[11];
    float* out = (float*)d_out;

    const int n = in_sizes[3];            // 100000
    const int e_cnt = in_sizes[1] / 2;    // 1600000
    const int nbk = (n + BK_COLS - 1) >> BK_SHIFT;          // 782 buckets
    const int chunk = (e_cnt + NBLK - 1) / NBLK;            // 25000 edges/block

    char* ws = (char*)d_ws;
    // --- small-matrix region first (fixed offsets) ---
    float*    Wo   = (float*)ws;                 // 8192 floats = 32KB
    float*    gG   = (float*)(ws + 32768);       // 12 x 4096 floats
    float*    gT   = gG  + 4096;
    float*    gA   = gT  + 4096;
    float*    gAn  = gA  + 4096;
    float*    gA0  = gAn + 4096;
    float*    gP   = gA0 + 4096;
    float*    gPn  = gP  + 4096;
    float*    gB0  = gPn + 4096;
    float*    gB1  = gB0 + 4096;
    float*    gB2  = gB1 + 4096;
    float*    gB3  = gB2 + 4096;
    float*    gB4  = gB3 + 4096;
    float*    gSc  = gB4 + 4096;                 // 2 floats (pad to 64)
    // --- big arrays ---
    float*          d_e2m    = gSc + 64;               // n
    float*          d_e3p    = d_e2m + n;              // n
    float*          gso2     = d_e3p + n;              // n
    unsigned short* xwb      = (unsigned short*)(gso2 + n);   // n*64 bf16
    unsigned*       blk_hist = (unsigned*)(xwb + (size_t)n * DOUT); // NBLK*1024
    unsigned*       boff     = blk_hist + (size_t)NBLK * NBK_STRIDE; // nbk+1
    uintptr_t pp = ((uintptr_t)(boff + nbk + 8) + 15) & ~(uintptr_t)15;
    uint2*          pairs    = (uint2*)pp;                     // e_cnt (8B)

    // ---- Bjorck chain: small multi-block dispatches ------------------------
    gram_pass<<<8, 256, 0, stream>>>(W, gG);                              // G
    mm_pass<<<8, 256, 0, stream>>>(gG, nullptr, gG, gT, nullptr, nullptr); // H = G^2
    mm_pass<<<8, 256, 0, stream>>>(gT, nullptr, gT, gA, nullptr, nullptr); // H2 = G^4
    power_pass<<<1, 64, 0, stream>>>(gA, gSc);                            // sc, rs
    prep_pass<<<16, 256, 0, stream>>>(gG, gSc, gA0, gB0);                 // A0, B0
    mm_pass<<<8, 256, 0, stream>>>(gA0, nullptr, gB0, gT, nullptr, nullptr); // T = A0@B0
    mm_pass<<<8, 256, 0, stream>>>(gT, nullptr, gB0, gA, nullptr, gB1);   // A1 (+B1)
    mm_pass<<<16, 256, 0, stream>>>(gB0, gA, gB1, gP, gT, nullptr);       // P=B0B1, T=A1B1
    mm_pass<<<8, 256, 0, stream>>>(gT, nullptr, gB1, gAn, nullptr, gB2);  // A2 (+B2)
    mm_pass<<<16, 256, 0, stream>>>(gP, gAn, gB2, gPn, gT, nullptr);      // P=PB2, T=A2B2
    mm_pass<<<8, 256, 0, stream>>>(gT, nullptr, gB2, gA, nullptr, gB3);   // A3 (+B3)
    mm_pass<<<16, 256, 0, stream>>>(gPn, gA, gB3, gP, gT, nullptr);       // P=PB3, T=A3B3
    mm_pass<<<8, 256, 0, stream>>>(gT, nullptr, gB3, gAn, nullptr, gB4);  // A4 (+B4)
    mm_pass<<<8, 256, 0, stream>>>(gP, nullptr, gB4, gPn, nullptr, nullptr); // P final
    wo_pass<<<8, 256, 0, stream>>>(W, gPn, gSc, Wo);                      // Wo

    // ---- node prep + feature transform ------------------------------------
    node_prep<<<(n + 255) / 256, 256, 0, stream>>>(diags, m1, m2, m3, e1, e2, e3,
                                                   d_e2m, d_e3p, gso2, n);
    xw_kernel<<<(n + XN - 1) / XN, 256, 0, stream>>>(x, Wo, xwb, n);
    // ---- bucket binning -----------------------------------------------------
    b1_hist<<<NBLK, 256, 0, stream>>>(ei, blk_hist, e_cnt, chunk, nbk);
    s_scan<<<1, 1024, 0, stream>>>(blk_hist, boff, nbk, e_cnt);
    b2_scatter<<<NBLK, 256, 0, stream>>>(ei, d_e2m, blk_hist, pairs, e_cnt, chunk, nbk);
    // ---- fused bucket gather + softmax --------------------------------------
    bucket_gather<<<nbk, 512, 0, stream>>>(pairs, boff, d_e3p, xwb, gso2, b, out, n);
}

// Round 14
// 262.085 us; speedup vs baseline: 3.4968x; 3.4968x over previous
//
#include <hip/hip_runtime.h>
#include <math.h>

#define DIN 128
#define DOUT 64

#define NBLK 64             // binning blocks
#define BK_SHIFT 7          // 128 cols per bucket
#define BK_COLS 128
#define NBK_STRIDE 1024     // blk_hist row stride (buckets padded)
#define CCAP 4096           // max edges per bucket staged in LDS (mean ~2046)

__device__ __forceinline__ float safe_pow(float d, float e) {
    float p = powf(d, e);
    return isinf(p) ? 0.0f : p;
}

__device__ __forceinline__ float dot4(float4 a, float4 b) {
    return a.x * b.x + a.y * b.y + a.z * b.z + a.w * b.w;
}

// fp32 -> bf16 (round-to-nearest-even), as raw ushort
__device__ __forceinline__ unsigned short f32_to_bf16(float f) {
    unsigned bits = __float_as_uint(f);
    unsigned r = (bits + 0x7FFFu + ((bits >> 16) & 1u)) >> 16;
    return (unsigned short)r;
}
// bf16 (raw ushort) -> fp32
__device__ __forceinline__ float bf16_to_f32(unsigned short u) {
    return __uint_as_float((unsigned)u << 16);
}

// ---------------------------------------------------------------------------
// Plain multi-block 64x64 matmul: C = A @ B, Bsrc SYMMETRIC (rows read as
// cols). grid 8 (single) or 16 (dual: blocks 8..15 compute C2 = A2 @ B).
// Optional CB output (single passes only): CB = 1.5I - 0.5*C.
// ---------------------------------------------------------------------------
__global__ __launch_bounds__(256) void mm_pass(const float* A1, const float* A2,
                                               const float* Bsrc,
                                               float* C1, float* C2, float* CB) {
    int t = threadIdx.x;
    bool second = (blockIdx.x >= 8);
    int blk = blockIdx.x & 7;
    const float* As = second ? A2 : A1;
    float* Cs = second ? C2 : C1;
    int c = t & 63;
    int r0 = blk * 8 + (t >> 6) * 2;
    float acc0 = 0.f, acc1 = 0.f;
#pragma unroll
    for (int k4 = 0; k4 < 16; ++k4) {
        float4 b  = *(const float4*)&Bsrc[c * 64 + k4 * 4];
        float4 a0 = *(const float4*)&As[r0 * 64 + k4 * 4];
        float4 a1 = *(const float4*)&As[(r0 + 1) * 64 + k4 * 4];
        acc0 += dot4(a0, b);
        acc1 += dot4(a1, b);
    }
    Cs[r0 * 64 + c] = acc0;
    Cs[(r0 + 1) * 64 + c] = acc1;
    if (CB != nullptr && !second) {
        CB[r0 * 64 + c]       = ((r0 == c)     ? 1.5f : 0.0f) - 0.5f * acc0;
        CB[(r0 + 1) * 64 + c] = ((r0 + 1 == c) ? 1.5f : 0.0f) - 0.5f * acc1;
    }
}

// ---------------------------------------------------------------------------
// G = W @ W^T (64x64, K=128), 8 blocks.
// ---------------------------------------------------------------------------
__global__ __launch_bounds__(256) void gram_pass(const float* W, float* G) {
    int t = threadIdx.x;
    int c = t & 63;
    int r0 = blockIdx.x * 8 + (t >> 6) * 2;
    float acc0 = 0.f, acc1 = 0.f;
#pragma unroll
    for (int k4 = 0; k4 < 32; ++k4) {
        float4 b  = *(const float4*)&W[c * 128 + k4 * 4];
        float4 a0 = *(const float4*)&W[r0 * 128 + k4 * 4];
        float4 a1 = *(const float4*)&W[(r0 + 1) * 128 + k4 * 4];
        acc0 += dot4(a0, b);
        acc1 += dot4(a1, b);
    }
    G[r0 * 64 + c] = acc0;
    G[(r0 + 1) * 64 + c] = acc1;
}

// ---------------------------------------------------------------------------
// power iteration on H2 = G^4 (trace-scaled, 8 raw iters + Rayleigh), 1 wave.
// ---------------------------------------------------------------------------
__global__ __launch_bounds__(64) void power_pass(const float* gH2, float* gSc) {
    int t = threadIdx.x;
    float tr = gH2[t * 65];
#pragma unroll
    for (int d = 1; d < 64; d <<= 1) tr += __shfl_xor(tr, d);
    float inv_tr = 1.0f / tr;
    float4 g4[16];
#pragma unroll
    for (int j4 = 0; j4 < 16; ++j4) {
        float4 v = *(const float4*)&gH2[t * 64 + j4 * 4];
        v.x *= inv_tr; v.y *= inv_tr; v.z *= inv_tr; v.w *= inv_tr;
        g4[j4] = v;
    }
    unsigned h = (unsigned)t * 2654435761u;
    float xv = 0.5f + (float)((h >> 17) & 0x7fff) * (1.0f / 32768.0f);
    float yv = 0.f;
    for (int it = 0; it < 8; ++it) {
        float p0 = 0.f, p1 = 0.f, p2 = 0.f, p3 = 0.f;
#pragma unroll
        for (int j4 = 0; j4 < 16; ++j4) {
            float4 xx;
            xx.x = __shfl(xv, j4 * 4 + 0);
            xx.y = __shfl(xv, j4 * 4 + 1);
            xx.z = __shfl(xv, j4 * 4 + 2);
            xx.w = __shfl(xv, j4 * 4 + 3);
            float dd = dot4(g4[j4], xx);
            if (j4 < 4) p0 += dd; else if (j4 < 8) p1 += dd;
            else if (j4 < 12) p2 += dd; else p3 += dd;
        }
        yv = (p0 + p1) + (p2 + p3);
        if (it < 7) xv = yv;
    }
    float num = xv * yv, den = xv * xv;
#pragma unroll
    for (int d = 1; d < 64; d <<= 1) {
        num += __shfl_xor(num, d);
        den += __shfl_xor(den, d);
    }
    if (t == 0) {
        float lam_h2 = tr * num / den;        // = sigma^8
        float sig = powf(lam_h2, 0.125f);
        gSc[0] = 1.0f / (1.1f * sig);
        gSc[1] = 1.0f / (1.21f * sig * sig);
    }
}

// ---------------------------------------------------------------------------
// prep: A0 = rs*G;  B0 = 1.5I - 0.5*A0
// ---------------------------------------------------------------------------
__global__ __launch_bounds__(256) void prep_pass(const float* gG, const float* gSc,
                                                 float* gA0, float* gB0) {
    int idx = blockIdx.x * 256 + threadIdx.x;
    if (idx >= 4096) return;
    float rs = gSc[1];
    int r = idx >> 6, c = idx & 63;
    float a0 = rs * gG[idx];
    gA0[idx] = a0;
    gB0[idx] = ((r == c) ? 1.5f : 0.0f) - 0.5f * a0;
}

// ---------------------------------------------------------------------------
// Wo = sc * P @ W  (64x128), 8 blocks.
// ---------------------------------------------------------------------------
__global__ __launch_bounds__(256) void wo_pass(const float* W, const float* P,
                                               const float* gSc, float* Wo) {
    int t = threadIdx.x;
    int c = t & 63;
    int r0 = blockIdx.x * 8 + (t >> 6) * 2;
    float a00 = 0.f, a01 = 0.f, a10 = 0.f, a11 = 0.f;
#pragma unroll 4
    for (int j = 0; j < 64; ++j) {
        float p0 = P[r0 * 64 + j];
        float p1 = P[(r0 + 1) * 64 + j];
        float w0 = W[j * 128 + c];
        float w1 = W[j * 128 + c + 64];
        a00 += p0 * w0; a01 += p0 * w1;
        a10 += p1 * w0; a11 += p1 * w1;
    }
    float sc = gSc[0];
    Wo[r0 * 128 + c]            = sc * a00;
    Wo[r0 * 128 + c + 64]       = sc * a01;
    Wo[(r0 + 1) * 128 + c]      = sc * a10;
    Wo[(r0 + 1) * 128 + c + 64] = sc * a11;
}

// ---------------------------------------------------------------------------
// per-node prep
// ---------------------------------------------------------------------------
__global__ void node_prep(const float* __restrict__ diags,
                          const float* m1, const float* m2, const float* m3,
                          const float* e1, const float* e2, const float* e3,
                          float* __restrict__ d_e2m, float* __restrict__ d_e3p,
                          float* __restrict__ gso2, int n) {
    int i = blockIdx.x * blockDim.x + threadIdx.x;
    if (i >= n) return;
    float d = diags[i];
    float p1 = safe_pow(d, e1[0]);
    float p2 = safe_pow(d, e2[0]);
    float p3 = safe_pow(d, e3[0]);
    float vm2 = m2[0];
    d_e2m[i] = vm2 * p2;
    d_e3p[i] = p3;
    gso2[i] = m1[0] * p1 + vm2 * p2 * p3 + m3[0];
}

// ---------------------------------------------------------------------------
// xw = x @ Wo^T — register-tiled GEMM; OUTPUT IN BF16.
// ---------------------------------------------------------------------------
#define XN 64
#define XS 132
__global__ __launch_bounds__(256) void xw_kernel(const float* __restrict__ x,
                                                 const float* __restrict__ Wo,
                                                 unsigned short* __restrict__ xwb,
                                                 int n) {
    __shared__ __align__(16) float xs[XN * XS];
    __shared__ __align__(16) float ws[DOUT * XS];
    int t = threadIdx.x;
    int base = blockIdx.x * XN;
    for (int f = t; f < DOUT * (DIN / 4); f += 256) {
        int r = f >> 5, c = f & 31;
        *(float4*)&ws[r * XS + c * 4] = *(const float4*)&Wo[r * DIN + c * 4];
    }
    for (int f = t; f < XN * (DIN / 4); f += 256) {
        int r = f >> 5, c = f & 31;
        int node = base + r;
        float4 v = make_float4(0.f, 0.f, 0.f, 0.f);
        if (node < n) v = *(const float4*)&x[(size_t)node * DIN + c * 4];
        *(float4*)&xs[r * XS + c * 4] = v;
    }
    __syncthreads();
    int tn = t >> 4;
    int td = t & 15;
    float acc[4][4] = {};
#pragma unroll 2
    for (int k4 = 0; k4 < DIN / 4; ++k4) {
        float4 a[4], w[4];
#pragma unroll
        for (int r = 0; r < 4; ++r) a[r] = *(const float4*)&xs[(tn * 4 + r) * XS + k4 * 4];
#pragma unroll
        for (int c = 0; c < 4; ++c) w[c] = *(const float4*)&ws[(td + c * 16) * XS + k4 * 4];
#pragma unroll
        for (int r = 0; r < 4; ++r)
#pragma unroll
            for (int c = 0; c < 4; ++c) acc[r][c] += dot4(a[r], w[c]);
    }
#pragma unroll
    for (int r = 0; r < 4; ++r) {
        int node = base + tn * 4 + r;
        if (node >= n) break;
#pragma unroll
        for (int c = 0; c < 4; ++c)
            xwb[(size_t)node * DOUT + td + c * 16] = f32_to_bf16(acc[r][c]);
    }
}

// ---------------------------------------------------------------------------
// Sort pass B1: per-block bucket histograms (bucket = col >> 7).
// ---------------------------------------------------------------------------
__global__ __launch_bounds__(256) void b1_hist(const int* __restrict__ ei,
                                               unsigned* __restrict__ blk_hist,
                                               int e_cnt, int chunk, int nbk) {
    __shared__ int h[NBK_STRIDE];
    int b = blockIdx.x, t = threadIdx.x;
    for (int j = t; j < NBK_STRIDE; j += 256) h[j] = 0;
    __syncthreads();
    int lo = b * chunk, hi = min(lo + chunk, e_cnt);
    for (int e = lo + t; e < hi; e += 256)
        atomicAdd(&h[ei[e_cnt + e] >> BK_SHIFT], 1);
    __syncthreads();
    for (int j = t; j < nbk; j += 256)
        blk_hist[(size_t)b * NBK_STRIDE + j] = (unsigned)h[j];
}

// ---------------------------------------------------------------------------
// Sort pass S: scan bucket totals -> bucket_offsets + per-(block,bucket) bases.
// ---------------------------------------------------------------------------
__global__ __launch_bounds__(1024) void s_scan(unsigned* __restrict__ blk_hist,
                                               unsigned* __restrict__ bucket_offsets,
                                               int nbk, int e_cnt) {
    __shared__ int tot[1024];
    int t = threadIdx.x;
    int total = 0;
    if (t < nbk) {
        int run = 0;
        for (int b = 0; b < NBLK; ++b) {
            size_t idx = (size_t)b * NBK_STRIDE + t;
            int v = (int)blk_hist[idx];
            blk_hist[idx] = (unsigned)run;
            run += v;
        }
        total = run;
    }
    tot[t] = total;
    __syncthreads();
    for (int d = 1; d < 1024; d <<= 1) {
        int u = (t >= d) ? tot[t - d] : 0;
        __syncthreads();
        tot[t] += u;
        __syncthreads();
    }
    int excl = tot[t] - total;
    if (t < nbk) {
        bucket_offsets[t] = (unsigned)excl;
        for (int b = 0; b < NBLK; ++b)
            blk_hist[(size_t)b * NBK_STRIDE + t] += (unsigned)excl;
    }
    if (t == 0) bucket_offsets[nbk] = (unsigned)e_cnt;
}

// ---------------------------------------------------------------------------
// Sort pass B2: scatter packed (src<<7 | lcol) into reserved per-block runs.
// ---------------------------------------------------------------------------
__global__ __launch_bounds__(256) void b2_scatter(const int* __restrict__ ei,
                                                  const unsigned* __restrict__ blk_hist,
                                                  unsigned* __restrict__ bucketed,
                                                  int e_cnt, int chunk, int nbk) {
    __shared__ int cur[NBK_STRIDE];
    int b = blockIdx.x, t = threadIdx.x;
    for (int j = t; j < nbk; j += 256)
        cur[j] = (int)blk_hist[(size_t)b * NBK_STRIDE + j];
    __syncthreads();
    int lo = b * chunk, hi = min(lo + chunk, e_cnt);
    for (int e = lo + t; e < hi; e += 256) {
        int col = ei[e_cnt + e];
        int src = ei[e];
        int bkt = col >> BK_SHIFT;
        int pos = atomicAdd(&cur[bkt], 1);
        bucketed[pos] = ((unsigned)src << BK_SHIFT) | (unsigned)(col & (BK_COLS - 1));
    }
}

// ---------------------------------------------------------------------------
// Sort pass C: one block per bucket -> exact CSR. Emits (src, weight_f32)
// uint2 pairs so the gather needs NO random d_e2m lookups.
// ---------------------------------------------------------------------------
__global__ __launch_bounds__(256) void c_csr(const unsigned* __restrict__ bucketed,
                                             const unsigned* __restrict__ bucket_offsets,
                                             const float* __restrict__ d_e2m,
                                             int* __restrict__ offsets,
                                             uint2* __restrict__ pairs,
                                             int n, int e_cnt) {
    __shared__ unsigned sE[CCAP];
    __shared__ int sh[BK_COLS];
    __shared__ int sc[BK_COLS];
    __shared__ int pos_[BK_COLS];
    int b = blockIdx.x, t = threadIdx.x;
    int base = (int)bucket_offsets[b];
    int cnt = (int)bucket_offsets[b + 1] - base;
    bool fits = (cnt <= CCAP);
    if (fits)
        for (int i = t; i < cnt; i += 256) sE[i] = bucketed[base + i];
    if (t < BK_COLS) sh[t] = 0;
    __syncthreads();
    for (int i = t; i < cnt; i += 256) {
        unsigned p = fits ? sE[i] : bucketed[base + i];
        atomicAdd(&sh[p & (BK_COLS - 1)], 1);
    }
    __syncthreads();
    if (t < BK_COLS) sc[t] = sh[t];
    __syncthreads();
    for (int d = 1; d < BK_COLS; d <<= 1) {
        int u = 0;
        if (t < BK_COLS && t >= d) u = sc[t - d];
        __syncthreads();
        if (t < BK_COLS) sc[t] += u;
        __syncthreads();
    }
    if (t < BK_COLS) {
        int pre = sc[t] - sh[t];
        int gc = b * BK_COLS + t;
        if (gc < n) offsets[gc] = base + pre;
        pos_[t] = pre;
    }
    if (b == 0 && t == 0) offsets[n] = e_cnt;
    __syncthreads();
    for (int i = t; i < cnt; i += 256) {
        unsigned p = fits ? sE[i] : bucketed[base + i];
        int lc = (int)(p & (BK_COLS - 1));
        unsigned s = p >> BK_SHIFT;
        int q = atomicAdd(&pos_[lc], 1);
        uint2 o;
        o.x = s;
        o.y = __float_as_uint(d_e2m[s]);
        pairs[base + q] = o;
    }
}

// ---------------------------------------------------------------------------
// fused gather + self-loop + bias + log-softmax.
// ONE WAVE HANDLES TWO ADJACENT NODES (their CSR runs are contiguous):
// interleaved unroll-4 chains for both nodes keep 8 loads in flight on the
// common path while halving per-node pipeline drains (round-12 lesson:
// latency/drain-bound at avg degree 16).
// ---------------------------------------------------------------------------
__global__ __launch_bounds__(256) void gather_kernel(const int* __restrict__ offsets,
                                                     const uint2* __restrict__ pairs,
                                                     const float* __restrict__ d_e3p,
                                                     const unsigned short* __restrict__ xwb,
                                                     const float* __restrict__ gso2,
                                                     const float* __restrict__ b,
                                                     float* __restrict__ out, int n) {
    unsigned lane = threadIdx.x & 63;
    int wid = threadIdx.x >> 6;
    int node0 = blockIdx.x * 8 + wid * 2;
    if (node0 >= n) return;
    int node1 = node0 + 1;
    bool has1 = (node1 < n);
    int i0 = offsets[node0];
    int h0 = offsets[node0 + 1];
    int i1 = has1 ? h0 : 0;
    int h1 = has1 ? offsets[node1 + 1] : 0;

    float a0A = 0.f, a0B = 0.f, a1A = 0.f, a1B = 0.f;
    // main: both nodes advance 4 edges/iter -> 8 loads in flight
    while (i0 + 4 <= h0 && i1 + 4 <= h1) {
        uint2 p00 = pairs[i0 + 0], p01 = pairs[i0 + 1], p02 = pairs[i0 + 2], p03 = pairs[i0 + 3];
        uint2 p10 = pairs[i1 + 0], p11 = pairs[i1 + 1], p12 = pairs[i1 + 2], p13 = pairs[i1 + 3];
        float v00 = bf16_to_f32(xwb[p00.x * 64u + lane]);
        float v01 = bf16_to_f32(xwb[p01.x * 64u + lane]);
        float v02 = bf16_to_f32(xwb[p02.x * 64u + lane]);
        float v03 = bf16_to_f32(xwb[p03.x * 64u + lane]);
        float v10 = bf16_to_f32(xwb[p10.x * 64u + lane]);
        float v11 = bf16_to_f32(xwb[p11.x * 64u + lane]);
        float v12 = bf16_to_f32(xwb[p12.x * 64u + lane]);
        float v13 = bf16_to_f32(xwb[p13.x * 64u + lane]);
        a0A += __uint_as_float(p00.y) * v00 + __uint_as_float(p01.y) * v01;
        a0B += __uint_as_float(p02.y) * v02 + __uint_as_float(p03.y) * v03;
        a1A += __uint_as_float(p10.y) * v10 + __uint_as_float(p11.y) * v11;
        a1B += __uint_as_float(p12.y) * v12 + __uint_as_float(p13.y) * v13;
        i0 += 4; i1 += 4;
    }
    // tail node0
    for (; i0 + 2 <= h0; i0 += 2) {
        uint2 p0 = pairs[i0], p1 = pairs[i0 + 1];
        a0A += __uint_as_float(p0.y) * bf16_to_f32(xwb[p0.x * 64u + lane]);
        a0B += __uint_as_float(p1.y) * bf16_to_f32(xwb[p1.x * 64u + lane]);
    }
    if (i0 < h0) {
        uint2 p = pairs[i0];
        a0A += __uint_as_float(p.y) * bf16_to_f32(xwb[p.x * 64u + lane]);
    }
    // tail node1
    for (; i1 + 2 <= h1; i1 += 2) {
        uint2 p0 = pairs[i1], p1 = pairs[i1 + 1];
        a1A += __uint_as_float(p0.y) * bf16_to_f32(xwb[p0.x * 64u + lane]);
        a1B += __uint_as_float(p1.y) * bf16_to_f32(xwb[p1.x * 64u + lane]);
    }
    if (i1 < h1) {
        uint2 p = pairs[i1];
        a1A += __uint_as_float(p.y) * bf16_to_f32(xwb[p.x * 64u + lane]);
    }

    float b2 = 2.0f * b[lane];
    // epilogue node0
    {
        float xself = bf16_to_f32(xwb[(size_t)node0 * DOUT + lane]);
        float v = gso2[node0] * xself + b2 + d_e3p[node0] * (a0A + a0B);
        float m = v;
#pragma unroll
        for (int d = 1; d < 64; d <<= 1) m = fmaxf(m, __shfl_xor(m, d));
        float s = expf(v - m);
#pragma unroll
        for (int d = 1; d < 64; d <<= 1) s += __shfl_xor(s, d);
        out[(size_t)node0 * DOUT + lane] = v - m - logf(s);
    }
    // epilogue node1
    if (has1) {
        float xself = bf16_to_f32(xwb[(size_t)node1 * DOUT + lane]);
        float v = gso2[node1] * xself + b2 + d_e3p[node1] * (a1A + a1B);
        float m = v;
#pragma unroll
        for (int d = 1; d < 64; d <<= 1) m = fmaxf(m, __shfl_xor(m, d));
        float s = expf(v - m);
#pragma unroll
        for (int d = 1; d < 64; d <<= 1) s += __shfl_xor(s, d);
        out[(size_t)node1 * DOUT + lane] = v - m - logf(s);
    }
}

// ---------------------------------------------------------------------------
extern "C" void kernel_launch(void* const* d_in, const int* in_sizes, int n_in,
                              void* d_out, int out_size, void* d_ws, size_t ws_size,
                              hipStream_t stream) {
    const float* x     = (const float*)d_in[0];
    const int*   ei    = (const int*)d_in[1];
    const float* diags = (const float*)d_in[3];
    const float* W     = (const float*)d_in[4];
    const float* b     = (const float*)d_in[5];
    const float* m1    = (const float*)d_in[6];
    const float* m2    = (const float*)d_in[7];
    const float* m3    = (const float*)d_in[8];
    const float* e1    = (const float*)d_in[9];
    const float* e2    = (const float*)d_in[10];
    const float* e3    = (const float*)d_in[11];
    float* out = (float*)d_out;

    const int n = in_sizes[3];            // 100000
    const int e_cnt = in_sizes[1] / 2;    // 1600000
    const int nbk = (n + BK_COLS - 1) >> BK_SHIFT;          // 782 buckets
    const int chunk = (e_cnt + NBLK - 1) / NBLK;            // 25000 edges/block

    char* ws = (char*)d_ws;
    // --- small-matrix region first (fixed offsets) ---
    float*    Wo   = (float*)ws;                 // 8192 floats = 32KB
    float*    gG   = (float*)(ws + 32768);       // 12 x 4096 floats
    float*    gT   = gG  + 4096;
    float*    gA   = gT  + 4096;
    float*    gAn  = gA  + 4096;
    float*    gA0  = gAn + 4096;
    float*    gP   = gA0 + 4096;
    float*    gPn  = gP  + 4096;
    float*    gB0  = gPn + 4096;
    float*    gB1  = gB0 + 4096;
    float*    gB2  = gB1 + 4096;
    float*    gB3  = gB2 + 4096;
    float*    gB4  = gB3 + 4096;
    float*    gSc  = gB4 + 4096;                 // 2 floats (pad to 64)
    // --- big arrays ---
    float*          d_e2m    = gSc + 64;               // n
    float*          d_e3p    = d_e2m + n;              // n
    float*          gso2     = d_e3p + n;              // n
    unsigned short* xwb      = (unsigned short*)(gso2 + n);   // n*64 bf16
    int*            offsets  = (int*)(xwb + (size_t)n * DOUT); // n+4
    unsigned*       bucketed = (unsigned*)(offsets + n + 4);   // e_cnt
    unsigned*       blk_hist = bucketed + e_cnt;               // NBLK*1024
    unsigned*       boff     = blk_hist + (size_t)NBLK * NBK_STRIDE; // nbk+1
    uintptr_t pp = ((uintptr_t)(boff + nbk + 8) + 15) & ~(uintptr_t)15;
    uint2*          pairs    = (uint2*)pp;                     // e_cnt (8B)

    // ---- Bjorck chain: small multi-block dispatches ------------------------
    gram_pass<<<8, 256, 0, stream>>>(W, gG);                              // G
    mm_pass<<<8, 256, 0, stream>>>(gG, nullptr, gG, gT, nullptr, nullptr); // H = G^2
    mm_pass<<<8, 256, 0, stream>>>(gT, nullptr, gT, gA, nullptr, nullptr); // H2 = G^4
    power_pass<<<1, 64, 0, stream>>>(gA, gSc);                            // sc, rs
    prep_pass<<<16, 256, 0, stream>>>(gG, gSc, gA0, gB0);                 // A0, B0
    mm_pass<<<8, 256, 0, stream>>>(gA0, nullptr, gB0, gT, nullptr, nullptr); // T = A0@B0
    mm_pass<<<8, 256, 0, stream>>>(gT, nullptr, gB0, gA, nullptr, gB1);   // A1 (+B1)
    mm_pass<<<16, 256, 0, stream>>>(gB0, gA, gB1, gP, gT, nullptr);       // P=B0B1, T=A1B1
    mm_pass<<<8, 256, 0, stream>>>(gT, nullptr, gB1, gAn, nullptr, gB2);  // A2 (+B2)
    mm_pass<<<16, 256, 0, stream>>>(gP, gAn, gB2, gPn, gT, nullptr);      // P=PB2, T=A2B2
    mm_pass<<<8, 256, 0, stream>>>(gT, nullptr, gB2, gA, nullptr, gB3);   // A3 (+B3)
    mm_pass<<<16, 256, 0, stream>>>(gPn, gA, gB3, gP, gT, nullptr);       // P=PB3, T=A3B3
    mm_pass<<<8, 256, 0, stream>>>(gT, nullptr, gB3, gAn, nullptr, gB4);  // A4 (+B4)
    mm_pass<<<8, 256, 0, stream>>>(gP, nullptr, gB4, gPn, nullptr, nullptr); // P final
    wo_pass<<<8, 256, 0, stream>>>(W, gPn, gSc, Wo);                      // Wo

    // ---- node prep + feature transform ------------------------------------
    node_prep<<<(n + 255) / 256, 256, 0, stream>>>(diags, m1, m2, m3, e1, e2, e3,
                                                   d_e2m, d_e3p, gso2, n);
    xw_kernel<<<(n + XN - 1) / XN, 256, 0, stream>>>(x, Wo, xwb, n);
    // ---- two-level bucket sort -> CSR --------------------------------------
    b1_hist<<<NBLK, 256, 0, stream>>>(ei, blk_hist, e_cnt, chunk, nbk);
    s_scan<<<1, 1024, 0, stream>>>(blk_hist, boff, nbk, e_cnt);
    b2_scatter<<<NBLK, 256, 0, stream>>>(ei, blk_hist, bucketed, e_cnt, chunk, nbk);
    c_csr<<<nbk, 256, 0, stream>>>(bucketed, boff, d_e2m, offsets, pairs, n, e_cnt);
    // ---- fused gather + softmax --------------------------------------------
    gather_kernel<<<(n + 7) / 8, 256, 0, stream>>>(offsets, pairs, d_e3p,
                                                   xwb, gso2, b, out, n);
}